// Round 2
// baseline (243.163 us; speedup 1.0000x reference)
//
#include <hip/hip_runtime.h>

typedef unsigned int u32;

// ---------------------------------------------------------------------------
// PillarFeatureNet fused kernel (round 2: fp32 I/O, wave-per-pillar VALU)
//
// Inputs (float32 unless noted):
//   features     (N, 32, 4)
//   num_points   (N,)        int32
//   coors        (N, 4)      int32  [b, z, y, x]
//   W            (63, 9)
//   gamma/beta/running_mean/running_var (63,)
// Output (float32): (N, 64) = [max-pooled 63 channels | num_points]
// ---------------------------------------------------------------------------

#define XOFF ((float)(0.16 / 2.0 + 0.0))      // vx/2 + pc_range[0] = 0.08
#define YOFF ((float)(0.16 / 2.0 - 39.68))    // vy/2 + pc_range[1] = -39.6

__global__ __launch_bounds__(256, 4)
void pfn_kernel(const float* __restrict__ features,
                const int* __restrict__ num_points,
                const int* __restrict__ coors,
                const float* __restrict__ W,
                const float* __restrict__ gamma,
                const float* __restrict__ beta,
                const float* __restrict__ rmean,
                const float* __restrict__ rvar,
                float* __restrict__ out,
                int n_total)
{
    // per-wave staging: 32 points x 12 floats (9 used, pad to float4 multiple)
    __shared__ __align__(16) float lds[4][32 * 12];

    const int lane = threadIdx.x & 63;
    const int wid  = threadIdx.x >> 6;
    const int waves_total = gridDim.x * 4;
    const int gwave = blockIdx.x * 4 + wid;

    // ---- per-lane channel setup: fold BN into W row --------------------
    float wrow[9];
#pragma unroll
    for (int c = 0; c < 9; ++c) wrow[c] = 0.0f;
    float shift = 0.0f;
    if (lane < 63) {
        const float inv = gamma[lane] / sqrtf(rvar[lane] + 1e-3f);
#pragma unroll
        for (int c = 0; c < 9; ++c)
            wrow[c] = W[lane * 9 + c] * inv;
        shift = beta[lane] - rmean[lane] * inv;
    }

    const int iters = (n_total + waves_total - 1) / waves_total;
    const float4* featv = reinterpret_cast<const float4*>(features);  // one point per float4

    for (int it = 0; it < iters; ++it) {
        const int n = gwave + it * waves_total;
        const bool active = (n < n_total);

        int npts = 1;
        float f0 = 0.f, f1 = 0.f, f2 = 0.f, f3 = 0.f;
        float cxo = 0.f, cyo = 0.f;
        if (active) {
            npts = num_points[n];
            const int ciy = coors[n * 4 + 2];
            const int cix = coors[n * 4 + 3];
            cxo = (float)cix * 0.16f + XOFF;
            cyo = (float)ciy * 0.16f + YOFF;
            if (lane < 32) {
                const float4 q = featv[(size_t)n * 32 + lane];
                f0 = q.x; f1 = q.y; f2 = q.z; f3 = q.w;
            }
        }

        // centroid mean: reference sums ALL 32 points (incl. padding), / num_points
        float sx = f0, sy = f1, sz = f2;
#pragma unroll
        for (int d = 1; d < 32; d <<= 1) {
            sx += __shfl_xor(sx, d, 32);
            sy += __shfl_xor(sy, d, 32);
            sz += __shfl_xor(sz, d, 32);
        }

        if (lane < 32) {
            const float rnp = 1.0f / (float)npts;
            const float mx = sx * rnp, my = sy * rnp, mz = sz * rnp;
            const bool valid = lane < npts;   // mask zeroes padded rows pre-linear
            float4 w0, w1, w2;
            if (valid) {
                w0 = make_float4(f0, f1, f2, f3);
                w1 = make_float4(f0 - mx, f1 - my, f2 - mz, f0 - cxo);
                w2 = make_float4(f1 - cyo, 0.f, 0.f, 0.f);
            } else {
                w0 = make_float4(0.f, 0.f, 0.f, 0.f);
                w1 = w0;
                w2 = w0;
            }
            float4* dst = reinterpret_cast<float4*>(&lds[wid][lane * 12]);
            dst[0] = w0;
            dst[1] = w1;
            dst[2] = w2;
        }
        __syncthreads();

        // lane u computes channel u: max over 32 points of (feats . wrow) + shift
        float maxv = -3.0e38f;
        const float* fl = lds[wid];
#pragma unroll 4
        for (int m = 0; m < 32; ++m) {
            const float4 a = *reinterpret_cast<const float4*>(fl + m * 12);
            const float4 b = *reinterpret_cast<const float4*>(fl + m * 12 + 4);
            const float c8 = fl[m * 12 + 8];
            float v = shift;
            v = fmaf(a.x, wrow[0], v);
            v = fmaf(a.y, wrow[1], v);
            v = fmaf(a.z, wrow[2], v);
            v = fmaf(a.w, wrow[3], v);
            v = fmaf(b.x, wrow[4], v);
            v = fmaf(b.y, wrow[5], v);
            v = fmaf(b.z, wrow[6], v);
            v = fmaf(b.w, wrow[7], v);
            v = fmaf(c8,  wrow[8], v);
            maxv = fmaxf(maxv, v);
        }
        maxv = fmaxf(maxv, 0.0f);   // relu(max) == max(relu) (monotone affine per channel)
        __syncthreads();

        if (active) {
            const float res = (lane == 63) ? (float)npts : maxv;
            out[(size_t)n * 64 + lane] = res;
        }
    }
}

extern "C" void kernel_launch(void* const* d_in, const int* in_sizes, int n_in,
                              void* d_out, int out_size, void* d_ws, size_t ws_size,
                              hipStream_t stream) {
    const float* features   = (const float*)d_in[0];
    const int*   num_points = (const int*)d_in[1];
    const int*   coors      = (const int*)d_in[2];
    const float* W          = (const float*)d_in[3];
    const float* gamma      = (const float*)d_in[4];
    const float* beta       = (const float*)d_in[5];
    const float* rmean      = (const float*)d_in[6];
    const float* rvar       = (const float*)d_in[7];
    float* out              = (float*)d_out;

    const int n_total = in_sizes[1];   // N = number of pillars

    // 2048 blocks x 4 waves = 8192 waves; ~15 pillars/wave grid-stride.
    const int blocks = 2048;
    pfn_kernel<<<blocks, 256, 0, stream>>>(features, num_points, coors, W,
                                           gamma, beta, rmean, rvar, out, n_total);
}

// Round 3
// 135.095 us; speedup vs baseline: 1.7999x; 1.7999x over previous
//
#include <hip/hip_runtime.h>

typedef unsigned int u32;
typedef unsigned short u16;
typedef __attribute__((ext_vector_type(8))) short bf16x8;    // 8 bf16 = 4 VGPRs (MFMA A/B frag)
typedef __attribute__((ext_vector_type(16))) float f32x16;   // MFMA C/D frag
typedef __attribute__((ext_vector_type(4))) u32 u32x4;

// ---------------------------------------------------------------------------
// PillarFeatureNet fused (round 3: MFMA 32x32x16 bf16, 2 pillars per wave)
//
//   features (N,32,4) f32 | num_points (N,) i32 | coors (N,4) i32 [b,z,y,x]
//   W (63,9) f32 | gamma/beta/running_mean/running_var (63,) f32
//   out (N,64) f32 = [relu(max-pool BN(linear(feats9)))[63] | num_points]
//
// Wave layout: lanes 0-31 own pillar A's 32 points, lanes 32-63 pillar B's.
// Per pillar: D(32pts x 64ch) = A(32x16 bf16 feats) * B(16x64 bf16 W') via
// two 32x32x16 MFMAs; row-max via 15 v_max + one xor-32 shuffle; BN shift
// and relu applied after the pool (shift is point-invariant => commutes).
// Masked points (m >= num_points) are zero rows => contribute relu(shift),
// exactly matching the reference's mask-then-linear-then-max.
// ---------------------------------------------------------------------------

#define XOFF (0.08f)            // vx/2 + pc_range[0]
#define YOFF (0.08f - 39.68f)   // vy/2 + pc_range[1]

__device__ __forceinline__ u32 f2bf_bits(float f) {
    union { float f; u32 u; } v; v.f = f;
    u32 u = v.u;
    u += 0x7fffu + ((u >> 16) & 1u);   // RNE
    return u >> 16;
}
__device__ __forceinline__ u32 pk2(float lo, float hi) {
    return f2bf_bits(lo) | (f2bf_bits(hi) << 16);
}
__device__ __forceinline__ short bf1(float f) { return (short)f2bf_bits(f); }

__device__ __forceinline__ float vmax16(const f32x16 v) {
    float a = fmaxf(fmaxf(v[0], v[1]), fmaxf(v[2], v[3]));
    float b = fmaxf(fmaxf(v[4], v[5]), fmaxf(v[6], v[7]));
    float c = fmaxf(fmaxf(v[8], v[9]), fmaxf(v[10], v[11]));
    float d = fmaxf(fmaxf(v[12], v[13]), fmaxf(v[14], v[15]));
    return fmaxf(fmaxf(a, b), fmaxf(c, d));
}

__global__ __launch_bounds__(256, 4)
void pfn_mfma(const float* __restrict__ features,
              const int* __restrict__ num_points,
              const int* __restrict__ coors,
              const float* __restrict__ W,
              const float* __restrict__ gamma,
              const float* __restrict__ beta,
              const float* __restrict__ rmean,
              const float* __restrict__ rvar,
              float* __restrict__ out,
              int n_total)
{
    // per-wave staging: 64 points x 24 u16 (48 B: 9 bf16 + zero pad to K=16)
    // stride 48 B => lanes alias banks 2-way (free, m136)
    __shared__ __align__(16) u16 lds[4][64 * 24];

    const int lane = threadIdx.x & 63;
    const int wid  = threadIdx.x >> 6;
    const int half = lane >> 5;          // 0 = pillar A, 1 = pillar B
    const int m    = lane & 31;          // point index (load) / channel col (epilogue)
    const int waves_total = gridDim.x * 4;
    const int gwave = blockIdx.x * 4 + wid;

    // ---- per-wave setup: fold BN into W, build B-frags -------------------
    // tile0 channels 0..31, tile1 channels 32..63 (ch 63 = dummy, overwritten)
    const int c0 = m, c1 = 32 + m;
    const float inv0   = gamma[c0] / sqrtf(rvar[c0] + 1e-3f);
    const float shift0 = beta[c0] - rmean[c0] * inv0;
    float inv1 = 0.0f, shift1 = 0.0f;
    if (c1 < 63) {
        inv1   = gamma[c1] / sqrtf(rvar[c1] + 1e-3f);
        shift1 = beta[c1] - rmean[c1] * inv1;
    }
    const float shift_me = half ? shift1 : shift0;   // == shift[channel lane]

    // B[k][n]: n = lane&31 (channel within tile), k = (lane>>5)*8 + j
    bf16x8 b0, b1;
#pragma unroll
    for (int j = 0; j < 8; ++j) {
        const int k = half * 8 + j;
        const float w0v = (k < 9) ? W[c0 * 9 + k] * inv0 : 0.0f;
        const float w1v = (k < 9 && c1 < 63) ? W[c1 * 9 + k] * inv1 : 0.0f;
        b0[j] = bf1(w0v);
        b1[j] = bf1(w1v);
    }

    const float4* featv = reinterpret_cast<const float4*>(features);
    const int pairs_per_sweep = waves_total;           // each wave: 2 pillars/iter
    const int iters = (n_total + 2 * waves_total - 1) / (2 * waves_total);

    for (int it = 0; it < iters; ++it) {
        const int pair = gwave + it * pairs_per_sweep;
        const int nA   = pair * 2;            // pillar A index
        const int n_h  = nA + half;           // this half's pillar
        const bool act = (n_h < n_total);

        // ---- per-point feature compute (fp32) ----
        const int npts = act ? num_points[n_h] : 1;
        float cxo = 0.f, cyo = 0.f;
        float4 q = make_float4(0.f, 0.f, 0.f, 0.f);
        if (act) {
            cxo = (float)coors[n_h * 4 + 3] * 0.16f + XOFF;
            cyo = (float)coors[n_h * 4 + 2] * 0.16f + YOFF;
            q = featv[(size_t)n_h * 32 + m];
        }

        // centroid: reference sums ALL 32 points (incl. padding), / num_points
        float sx = q.x, sy = q.y, sz = q.z;
#pragma unroll
        for (int d = 1; d < 32; d <<= 1) {
            sx += __shfl_xor(sx, d, 32);
            sy += __shfl_xor(sy, d, 32);
            sz += __shfl_xor(sz, d, 32);
        }
        const float rnp = 1.0f / (float)npts;
        const float mx = sx * rnp, my = sy * rnp, mz = sz * rnp;

        const bool valid = (m < npts);
        float f0 = 0.f, f1 = 0.f, f2 = 0.f, f3 = 0.f, f4 = 0.f,
              f5 = 0.f, f6 = 0.f, f7 = 0.f, f8 = 0.f;
        if (valid) {
            f0 = q.x; f1 = q.y; f2 = q.z; f3 = q.w;
            f4 = q.x - mx; f5 = q.y - my; f6 = q.z - mz;
            f7 = q.x - cxo; f8 = q.y - cyo;
        }

        // ---- stage to LDS as bf16, K padded to 16 ----
        u16* row = &lds[wid][lane * 24];
        u32x4 lodw; lodw[0] = pk2(f0, f1); lodw[1] = pk2(f2, f3);
        lodw[2] = pk2(f4, f5); lodw[3] = pk2(f6, f7);
        u32x4 hidw; hidw[0] = pk2(f8, 0.f); hidw[1] = 0; hidw[2] = 0; hidw[3] = 0;
        reinterpret_cast<u32x4*>(row)[0] = lodw;
        reinterpret_cast<u32x4*>(row)[1] = hidw;
        __syncthreads();

        // ---- A-frags: A[m=lane&31][k=(lane>>5)*8+j] ----
        const bf16x8 aA = *reinterpret_cast<const bf16x8*>(&lds[wid][m * 24 + half * 8]);
        const bf16x8 aB = *reinterpret_cast<const bf16x8*>(&lds[wid][(32 + m) * 24 + half * 8]);

        f32x16 cA0 = {}, cA1 = {}, cB0 = {}, cB1 = {};
        cA0 = __builtin_amdgcn_mfma_f32_32x32x16_bf16(aA, b0, cA0, 0, 0, 0);
        cA1 = __builtin_amdgcn_mfma_f32_32x32x16_bf16(aA, b1, cA1, 0, 0, 0);
        cB0 = __builtin_amdgcn_mfma_f32_32x32x16_bf16(aB, b0, cB0, 0, 0, 0);
        cB1 = __builtin_amdgcn_mfma_f32_32x32x16_bf16(aB, b1, cB1, 0, 0, 0);

        // ---- epilogue: row-max (16 regs in-lane, then xor-32 half merge) ----
        float tA0 = vmax16(cA0), tA1 = vmax16(cA1);
        float tB0 = vmax16(cB0), tB1 = vmax16(cB1);
        tA0 = fmaxf(tA0, __shfl_xor(tA0, 32));
        tA1 = fmaxf(tA1, __shfl_xor(tA1, 32));
        tB0 = fmaxf(tB0, __shfl_xor(tB0, 32));
        tB1 = fmaxf(tB1, __shfl_xor(tB1, 32));

        float vA = fmaxf((half ? tA1 : tA0) + shift_me, 0.0f);
        float vB = fmaxf((half ? tB1 : tB0) + shift_me, 0.0f);

        // channel 63 = num_points; lane 63 needs BOTH pillars' counts
        const float npf = (float)npts;
        const float npA = __shfl(npf, 0);
        const float npB = __shfl(npf, 32);
        if (lane == 63) { vA = npA; vB = npB; }

        if (nA < n_total)     out[(size_t)nA * 64 + lane] = vA;
        if (nA + 1 < n_total) out[(size_t)(nA + 1) * 64 + lane] = vB;

        __syncthreads();   // protect LDS region before next iter's writes
    }
}

extern "C" void kernel_launch(void* const* d_in, const int* in_sizes, int n_in,
                              void* d_out, int out_size, void* d_ws, size_t ws_size,
                              hipStream_t stream) {
    const float* features   = (const float*)d_in[0];
    const int*   num_points = (const int*)d_in[1];
    const int*   coors      = (const int*)d_in[2];
    const float* W          = (const float*)d_in[3];
    const float* gamma      = (const float*)d_in[4];
    const float* beta       = (const float*)d_in[5];
    const float* rmean      = (const float*)d_in[6];
    const float* rvar       = (const float*)d_in[7];
    float* out              = (float*)d_out;

    const int n_total = in_sizes[1];   // N pillars

    // 1024 blocks x 4 waves = 4096 waves x 2 pillars = 8192 pillars/sweep,
    // ~15 sweeps. 4 blocks/CU co-resident at launch_bounds(256,4).
    const int blocks = 1024;
    pfn_mfma<<<blocks, 256, 0, stream>>>(features, num_points, coors, W,
                                         gamma, beta, rmean, rvar, out, n_total);
}

// Round 4
// 132.772 us; speedup vs baseline: 1.8314x; 1.0175x over previous
//
#include <hip/hip_runtime.h>
#include <hip/hip_bf16.h>

typedef unsigned int u32;
typedef unsigned short u16;
typedef __attribute__((ext_vector_type(8))) short bf16x8;    // 8 bf16 = 4 VGPRs (MFMA A/B frag)
typedef __attribute__((ext_vector_type(16))) float f32x16;   // MFMA C/D frag
typedef __attribute__((ext_vector_type(4))) u32 u32x4;

// ---------------------------------------------------------------------------
// PillarFeatureNet fused (round 4: barrier-free MFMA, shuffle transpose)
//
//   features (N,32,4) f32 | num_points (N,) i32 | coors (N,4) i32 [b,z,y,x]
//   W (63,9) f32 | gamma/beta/running_mean/running_var (63,) f32
//   out (N,64) f32 = [relu(max-pool BN(linear(feats9)))[63] | num_points]
//
// Wave layout: lanes 0-31 = pillar A's 32 points, lanes 32-63 = pillar B's.
// A-fragment for 32x32x16 MFMA needs A[m=lane&31][k=half*8+j]; since each
// lane owns all 9 features of its point, the frag is built with FIVE
// __shfl_xor(..,32) ops (f0..f7 dwords one way, f8 the other) — no LDS, no
// __syncthreads. Waves are fully independent -> occupancy hides load latency.
// BN shift is point-invariant => relu(max_raw + shift) after the pool.
// Masked points are zero rows => contribute relu(shift), matching reference.
// ---------------------------------------------------------------------------

#define XOFF (0.08f)            // vx/2 + pc_range[0]
#define YOFF (0.08f - 39.68f)   // vy/2 + pc_range[1]

__device__ __forceinline__ u32 f2bf_bits(float f) {
    union { float f; u32 u; } v; v.f = f;
    u32 u = v.u;
    u += 0x7fffu + ((u >> 16) & 1u);   // RNE
    return u >> 16;
}
__device__ __forceinline__ short bf1(float f) { return (short)f2bf_bits(f); }

// packed bf16 convert: v_cvt_pk_bf16_f32 (1 instr) via hip_bf16 helper
__device__ __forceinline__ u32 pk2(float lo, float hi) {
    __hip_bfloat162 h = __float22bfloat162_rn(make_float2(lo, hi));
    union { __hip_bfloat162 h; u32 u; } v; v.h = h;
    return v.u;   // low 16 bits = lo, high = hi
}

__device__ __forceinline__ float vmax16(const f32x16 v) {
    // written as balanced trees so the compiler fuses v_max3_f32
    float a = fmaxf(fmaxf(v[0], v[1]), fmaxf(v[2], v[3]));
    float b = fmaxf(fmaxf(v[4], v[5]), fmaxf(v[6], v[7]));
    float c = fmaxf(fmaxf(v[8], v[9]), fmaxf(v[10], v[11]));
    float d = fmaxf(fmaxf(v[12], v[13]), fmaxf(v[14], v[15]));
    return fmaxf(fmaxf(a, b), fmaxf(c, d));
}

__global__ __launch_bounds__(256, 4)
void pfn_mfma(const float* __restrict__ features,
              const int* __restrict__ num_points,
              const int* __restrict__ coors,
              const float* __restrict__ W,
              const float* __restrict__ gamma,
              const float* __restrict__ beta,
              const float* __restrict__ rmean,
              const float* __restrict__ rvar,
              float* __restrict__ out,
              int n_total)
{
    const int lane = threadIdx.x & 63;
    const int wid  = threadIdx.x >> 6;
    const int half = lane >> 5;          // 0 = pillar A, 1 = pillar B
    const int m    = lane & 31;          // point index / channel within tile
    const int waves_total = gridDim.x * 4;
    const int gwave = blockIdx.x * 4 + wid;

    // ---- per-wave setup: fold BN into W, build B-frags -------------------
    const int c0 = m, c1 = 32 + m;       // tile0 ch 0..31, tile1 ch 32..63
    const float inv0   = gamma[c0] / sqrtf(rvar[c0] + 1e-3f);
    const float shift0 = beta[c0] - rmean[c0] * inv0;
    float inv1 = 0.0f, shift1 = 0.0f;
    if (c1 < 63) {
        inv1   = gamma[c1] / sqrtf(rvar[c1] + 1e-3f);
        shift1 = beta[c1] - rmean[c1] * inv1;
    }
    const float shift_me = half ? shift1 : shift0;

    // B[k][n]: n = lane&31 (channel within tile), k = half*8 + j
    bf16x8 b0, b1;
#pragma unroll
    for (int j = 0; j < 8; ++j) {
        const int k = half * 8 + j;
        b0[j] = bf1((k < 9) ? W[c0 * 9 + k] * inv0 : 0.0f);
        b1[j] = bf1((k < 9 && c1 < 63) ? W[c1 * 9 + k] * inv1 : 0.0f);
    }

    const float4* featv = reinterpret_cast<const float4*>(features);
    const int iters = (n_total + 2 * waves_total - 1) / (2 * waves_total);

    // ---- register prefetch of iteration 0 --------------------------------
    float4 q = make_float4(0.f, 0.f, 0.f, 0.f);
    int   npts = 1;
    float cxo = 0.f, cyo = 0.f;
    {
        const int n_h = gwave * 2 + half;
        if (n_h < n_total) {
            npts = num_points[n_h];
            cxo = (float)coors[n_h * 4 + 3] * 0.16f + XOFF;
            cyo = (float)coors[n_h * 4 + 2] * 0.16f + YOFF;
            q = featv[(size_t)n_h * 32 + m];
        }
    }

    for (int it = 0; it < iters; ++it) {
        const int nA = (gwave + it * waves_total) * 2;

        // ---- prefetch next iteration (stays in flight across the body) ----
        float4 qn = make_float4(0.f, 0.f, 0.f, 0.f);
        int   npn = 1;
        float cxn = 0.f, cyn = 0.f;
        if (it + 1 < iters) {
            const int n_h = (gwave + (it + 1) * waves_total) * 2 + half;
            if (n_h < n_total) {
                npn = num_points[n_h];
                cxn = (float)coors[n_h * 4 + 3] * 0.16f + XOFF;
                cyn = (float)coors[n_h * 4 + 2] * 0.16f + YOFF;
                qn = featv[(size_t)n_h * 32 + m];
            }
        }

        // ---- centroid: sum ALL 32 points (incl. padding), / num_points ----
        float sx = q.x, sy = q.y, sz = q.z;
#pragma unroll
        for (int d = 1; d < 32; d <<= 1) {
            sx += __shfl_xor(sx, d, 32);
            sy += __shfl_xor(sy, d, 32);
            sz += __shfl_xor(sz, d, 32);
        }
        const float rnp = 1.0f / (float)npts;
        const float mx = sx * rnp, my = sy * rnp, mz = sz * rnp;

        // ---- 9-dim feature, packed bf16, masked ---------------------------
        u32 p0 = pk2(q.x, q.y);
        u32 p1 = pk2(q.z, q.w);
        u32 p2 = pk2(q.x - mx, q.y - my);
        u32 p3 = pk2(q.z - mz, q.x - cxo);
        u32 p4 = pk2(q.y - cyo, 0.0f);
        if (m >= npts) { p0 = 0; p1 = 0; p2 = 0; p3 = 0; p4 = 0; }

        // ---- cross-half exchange: 5 shuffles replace the LDS transpose ----
        const u32 x0 = __shfl_xor(p0, 32);
        const u32 x1 = __shfl_xor(p1, 32);
        const u32 x2 = __shfl_xor(p2, 32);
        const u32 x3 = __shfl_xor(p3, 32);
        const u32 x4 = __shfl_xor(p4, 32);

        // aA: lanes<32 hold pillar A's k=0..7 (own p0..p3);
        //     lanes>=32 hold pillar A's k=8..15 (partner's f8 = x4, rest 0)
        u32x4 adw, bdw;
        adw[0] = half ? x4 : p0;  adw[1] = half ? 0u : p1;
        adw[2] = half ? 0u : p2;  adw[3] = half ? 0u : p3;
        // aB: lanes<32 hold pillar B's k=0..7 (partner's x0..x3);
        //     lanes>=32 hold pillar B's k=8..15 (own f8 = p4, rest 0)
        bdw[0] = half ? p4 : x0;  bdw[1] = half ? 0u : x1;
        bdw[2] = half ? 0u : x2;  bdw[3] = half ? 0u : x3;
        const bf16x8 aA = __builtin_bit_cast(bf16x8, adw);
        const bf16x8 aB = __builtin_bit_cast(bf16x8, bdw);

        f32x16 cA0 = {}, cA1 = {}, cB0 = {}, cB1 = {};
        cA0 = __builtin_amdgcn_mfma_f32_32x32x16_bf16(aA, b0, cA0, 0, 0, 0);
        cA1 = __builtin_amdgcn_mfma_f32_32x32x16_bf16(aA, b1, cA1, 0, 0, 0);
        cB0 = __builtin_amdgcn_mfma_f32_32x32x16_bf16(aB, b0, cB0, 0, 0, 0);
        cB1 = __builtin_amdgcn_mfma_f32_32x32x16_bf16(aB, b1, cB1, 0, 0, 0);

        // ---- epilogue: row-max (in-lane 16, then xor-32 half merge) -------
        float tA0 = vmax16(cA0), tA1 = vmax16(cA1);
        float tB0 = vmax16(cB0), tB1 = vmax16(cB1);
        tA0 = fmaxf(tA0, __shfl_xor(tA0, 32));
        tA1 = fmaxf(tA1, __shfl_xor(tA1, 32));
        tB0 = fmaxf(tB0, __shfl_xor(tB0, 32));
        tB1 = fmaxf(tB1, __shfl_xor(tB1, 32));

        float vA = fmaxf((half ? tA1 : tA0) + shift_me, 0.0f);
        float vB = fmaxf((half ? tB1 : tB0) + shift_me, 0.0f);

        // channel 63 = num_points; lane 63 needs BOTH pillars' counts
        const float npf = (float)npts;
        const float npA = __shfl(npf, 0);
        const float npB = __shfl(npf, 32);
        if (lane == 63) { vA = npA; vB = npB; }

        if (nA < n_total)     out[(size_t)nA * 64 + lane] = vA;
        if (nA + 1 < n_total) out[(size_t)(nA + 1) * 64 + lane] = vB;

        // rotate prefetch registers
        q = qn; npts = npn; cxo = cxn; cyo = cyn;
    }
}

extern "C" void kernel_launch(void* const* d_in, const int* in_sizes, int n_in,
                              void* d_out, int out_size, void* d_ws, size_t ws_size,
                              hipStream_t stream) {
    const float* features   = (const float*)d_in[0];
    const int*   num_points = (const int*)d_in[1];
    const int*   coors      = (const int*)d_in[2];
    const float* W          = (const float*)d_in[3];
    const float* gamma      = (const float*)d_in[4];
    const float* beta       = (const float*)d_in[5];
    const float* rmean      = (const float*)d_in[6];
    const float* rvar       = (const float*)d_in[7];
    float* out              = (float*)d_out;

    const int n_total = in_sizes[1];   // N pillars

    // 1024 blocks x 4 waves = 4096 waves x 2 pillars/iter, ~15 iters.
    // No LDS, no barriers; launch_bounds(256,4) caps VGPR at 128.
    const int blocks = 1024;
    pfn_mfma<<<blocks, 256, 0, stream>>>(features, num_points, coors, W,
                                         gamma, beta, rmean, rvar, out, n_total);
}